// Round 1
// baseline (778.046 us; speedup 1.0000x reference)
//
#include <hip/hip_runtime.h>
#include <hip/hip_bf16.h>

// Problem constants: T=1024, B=64, I=512, H=512, L=2. 4H=2048. K=512.
#define T_DIM 1024
#define B_DIM 64
#define H_DIM 512

typedef __attribute__((ext_vector_type(8))) short short8;
typedef __attribute__((ext_vector_type(4))) float f32x4;

typedef __attribute__((address_space(3))) void lds_void_t;
typedef __attribute__((address_space(1))) void glob_void_t;

static __device__ __forceinline__ unsigned short f2b_rne(float f) {
  unsigned u = __float_as_uint(f);
  u += 0x7fffu + ((u >> 16) & 1u);
  return (unsigned short)(u >> 16);
}

static __device__ __forceinline__ float sigm(float x) {
  return 1.0f / (1.0f + __expf(-x));
}
// NaN-safe fast tanh: uses |x| so exp never produces inf-inf.
static __device__ __forceinline__ float tanh_fast(float x) {
  float e = __expf(2.0f * fabsf(x));
  float t = 1.0f - 2.0f / (e + 1.0f);
  return copysignf(t, x);
}

// ---------------- fp32 -> bf16 conversion (vectorized x4, grid-stride) ------
__global__ void conv_f2b(const float* __restrict__ in,
                         unsigned short* __restrict__ out, int n4) {
  int idx = blockIdx.x * blockDim.x + threadIdx.x;
  int stride = gridDim.x * blockDim.x;
  for (int i = idx; i < n4; i += stride) {
    float4 v = reinterpret_cast<const float4*>(in)[i];
    ushort4 o;
    o.x = f2b_rne(v.x); o.y = f2b_rne(v.y);
    o.z = f2b_rne(v.z); o.w = f2b_rne(v.w);
    reinterpret_cast<ushort4*>(out)[i] = o;
  }
}

// ---------------- hhb[l][b][g] = b_ih[g] + b_hh[g] + sum_k h0[l,b,k]*w_hh[g,k]
// grid (8, 64, 2), block 256
__global__ void hh_bias(const float* __restrict__ h0,
                        const float* __restrict__ whh0, const float* __restrict__ whh1,
                        const float* __restrict__ bih0, const float* __restrict__ bhh0,
                        const float* __restrict__ bih1, const float* __restrict__ bhh1,
                        float* __restrict__ hhb) {
  int g = blockIdx.x * blockDim.x + threadIdx.x;  // 0..2047
  int b = blockIdx.y;
  int l = blockIdx.z;
  const float* wh = l ? whh1 : whh0;
  const float* bi = l ? bih1 : bih0;
  const float* bh = l ? bhh1 : bhh0;
  const float4* hr = reinterpret_cast<const float4*>(h0 + ((size_t)l * B_DIM + b) * H_DIM);
  const float4* wr = reinterpret_cast<const float4*>(wh + (size_t)g * H_DIM);
  float acc = bi[g] + bh[g];
#pragma unroll 4
  for (int k = 0; k < H_DIM / 4; ++k) {
    float4 a = hr[k], w = wr[k];
    acc += a.x * w.x + a.y * w.y + a.z * w.z + a.w * w.w;
  }
  hhb[((size_t)l * B_DIM + b) * 2048 + g] = acc;
}

// ---------------- fused LSTM-layer GEMM -------------------------------------
// gates[m, gate*512+h] = sum_k A[m,k] * W[gate*512+h, k]   (B^T layout)
// Tile: 128 rows (m) x 32 h-cols x 4 gates = 128x128 effective GEMM tile.
// eff col n = gate*32 + (n&31) is remapped so that fragment index c:
//   gate = c>>1, h = h0 + (c&1)*16 + (lane&15)
// -> all 4 gates of one (m,h) live in ONE lane's accumulators -> fused epilogue.
// LDS: XOR-swizzled k-chunks (chunk ^= row&7) applied on the global SOURCE
// address during global_load_lds (linear dest) and on the ds_read address.
template <int LAYER>
__global__ __launch_bounds__(256, 2) void lstm_gemm(
    const unsigned short* __restrict__ Abf,   // [65536, 512] bf16
    const unsigned short* __restrict__ Wbf,   // [2048, 512]  bf16
    const float* __restrict__ hhb,            // [64, 2048] this layer
    const float* __restrict__ c0l,            // [64, 512]  this layer
    unsigned short* __restrict__ hy_bf,       // layer0: bf16 out (ws)
    float* __restrict__ out_hy,               // layer1: fp32 out (d_out)
    float* __restrict__ out_lasth,            // [64,512] this layer
    float* __restrict__ out_lastc) {          // [64,512] this layer
  __shared__ __attribute__((aligned(16))) unsigned short Alds[128 * 64];
  __shared__ __attribute__((aligned(16))) unsigned short Blds[128 * 64];

  const int tid = threadIdx.x;
  const int lane = tid & 63;
  const int wid = tid >> 6;
  const int bh = blockIdx.x;   // 0..15  (h-tile)
  const int bm = blockIdx.y;   // 0..511 (m-tile)
  const int m0 = bm * 128;
  const int h0 = bh * 32;
  const int lane_lo = lane & 15, lane_hi = lane >> 4;
  const int srow = tid >> 3;   // 0..31
  const int slot = tid & 7;

  f32x4 acc[2][8] = {};

  for (int ks = 0; ks < 8; ++ks) {
    const int k0 = ks * 64;
    // stage A tile [128][64] (linear LDS dest, inverse-swizzled source chunk)
#pragma unroll
    for (int i = 0; i < 4; ++i) {
      int row = i * 32 + srow;
      int sch = slot ^ (row & 7);
      const unsigned short* src = Abf + (size_t)(m0 + row) * 512 + k0 + sch * 8;
      char* dst = (char*)Alds + i * 4096 + wid * 1024;  // wave-uniform base
      __builtin_amdgcn_global_load_lds((const glob_void_t*)src, (lds_void_t*)dst, 16, 0, 0);
    }
    // stage B tile: eff-row n -> W row (n>>5)*512 + h0 + (n&31)
#pragma unroll
    for (int i = 0; i < 4; ++i) {
      int n = i * 32 + srow;
      int sch = slot ^ (n & 7);
      int wrow = (n >> 5) * H_DIM + h0 + (n & 31);
      const unsigned short* src = Wbf + (size_t)wrow * 512 + k0 + sch * 8;
      char* dst = (char*)Blds + i * 4096 + wid * 1024;
      __builtin_amdgcn_global_load_lds((const glob_void_t*)src, (lds_void_t*)dst, 16, 0, 0);
    }
    __syncthreads();

#pragma unroll
    for (int kk = 0; kk < 2; ++kk) {
      const int cbase = kk * 4 + lane_hi;  // k-chunk index (8 bf16 per chunk)
      short8 aF[2];
#pragma unroll
      for (int r = 0; r < 2; ++r) {
        int row = wid * 32 + r * 16 + lane_lo;
        aF[r] = *reinterpret_cast<const short8*>(
            (const char*)Alds + row * 128 + ((cbase ^ (row & 7)) << 4));
      }
      short8 bF[8];
#pragma unroll
      for (int c = 0; c < 8; ++c) {
        int n = c * 16 + lane_lo;
        bF[c] = *reinterpret_cast<const short8*>(
            (const char*)Blds + n * 128 + ((cbase ^ (n & 7)) << 4));
      }
#pragma unroll
      for (int r = 0; r < 2; ++r)
#pragma unroll
        for (int c = 0; c < 8; ++c)
          acc[r][c] = __builtin_amdgcn_mfma_f32_16x16x32_bf16(aF[r], bF[c], acc[r][c], 0, 0, 0);
    }
    __syncthreads();
  }

  // fused gate epilogue
#pragma unroll
  for (int r = 0; r < 2; ++r) {
#pragma unroll
    for (int j = 0; j < 4; ++j) {
      int m = m0 + wid * 32 + r * 16 + lane_hi * 4 + j;
      int b = m & (B_DIM - 1);
      bool isLast = (m >> 6) == (T_DIM - 1);
      const float* hb = hhb + (size_t)b * 2048;
#pragma unroll
      for (int hc = 0; hc < 2; ++hc) {
        int h = h0 + hc * 16 + lane_lo;
        float gi = acc[r][0 + hc][j] + hb[h];
        float gf = acc[r][2 + hc][j] + hb[512 + h];
        float gg = acc[r][4 + hc][j] + hb[1024 + h];
        float go = acc[r][6 + hc][j] + hb[1536 + h];
        float iv = sigm(gi), fv = sigm(gf), gv = tanh_fast(gg), ov = sigm(go);
        float cv = fv * c0l[b * H_DIM + h] + iv * gv;
        float hv = ov * tanh_fast(cv);
        if (LAYER == 0) {
          hy_bf[(size_t)m * H_DIM + h] = f2b_rne(hv);
        } else {
          out_hy[(size_t)m * H_DIM + h] = hv;
        }
        if (isLast) {
          out_lasth[b * H_DIM + h] = hv;
          out_lastc[b * H_DIM + h] = cv;
        }
      }
    }
  }
}

extern "C" void kernel_launch(void* const* d_in, const int* in_sizes, int n_in,
                              void* d_out, int out_size, void* d_ws, size_t ws_size,
                              hipStream_t stream) {
  const float* x    = (const float*)d_in[0];
  const float* h0   = (const float*)d_in[1];
  const float* c0   = (const float*)d_in[2];
  const float* wih0 = (const float*)d_in[3];
  const float* whh0 = (const float*)d_in[4];
  const float* bih0 = (const float*)d_in[5];
  const float* bhh0 = (const float*)d_in[6];
  const float* wih1 = (const float*)d_in[7];
  const float* whh1 = (const float*)d_in[8];
  const float* bih1 = (const float*)d_in[9];
  const float* bhh1 = (const float*)d_in[10];
  float* out = (float*)d_out;

  // workspace layout (bytes)
  char* ws = (char*)d_ws;
  unsigned short* x_bf   = (unsigned short*)(ws);              // 67108864 B
  unsigned short* hy0_bf = (unsigned short*)(ws + 67108864);   // 67108864 B
  unsigned short* w0_bf  = (unsigned short*)(ws + 134217728);  // 2097152 B
  unsigned short* w1_bf  = (unsigned short*)(ws + 136314880);  // 2097152 B
  float*          hhb    = (float*)(ws + 138412032);           // 1048576 B

  conv_f2b<<<2048, 256, 0, stream>>>(x, x_bf, 33554432 / 4);
  conv_f2b<<<512, 256, 0, stream>>>(wih0, w0_bf, 1048576 / 4);
  conv_f2b<<<512, 256, 0, stream>>>(wih1, w1_bf, 1048576 / 4);
  hh_bias<<<dim3(8, 64, 2), 256, 0, stream>>>(h0, whh0, whh1, bih0, bhh0, bih1, bhh1, hhb);

  float* res   = out;                         // [65536, 512]
  float* lasth = out + 33554432;              // [2, 64, 512]
  float* lastc = out + 33554432 + 65536;      // [2, 64, 512]

  // grid: x = h-tile (16) fastest -> consecutive blocks share the A panel (L2)
  lstm_gemm<0><<<dim3(16, 512), 256, 0, stream>>>(
      x_bf, w0_bf, hhb, c0, hy0_bf, nullptr, lasth, lastc);
  lstm_gemm<1><<<dim3(16, 512), 256, 0, stream>>>(
      hy0_bf, w1_bf, hhb + 64 * 2048, c0 + 64 * 512, nullptr, res,
      lasth + 64 * 512, lastc + 64 * 512);
}

// Round 3
// 674.914 us; speedup vs baseline: 1.1528x; 1.1528x over previous
//
#include <hip/hip_runtime.h>
#include <hip/hip_bf16.h>

// Problem constants: T=1024, B=64, I=512, H=512, L=2. 4H=2048. K=512.
#define T_DIM 1024
#define B_DIM 64
#define H_DIM 512

typedef __attribute__((ext_vector_type(8))) short short8;
typedef __attribute__((ext_vector_type(4))) float f32x4;

typedef __attribute__((address_space(3))) void lds_void_t;
typedef __attribute__((address_space(1))) void glob_void_t;

static __device__ __forceinline__ unsigned short f2b_rne(float f) {
  unsigned u = __float_as_uint(f);
  u += 0x7fffu + ((u >> 16) & 1u);
  return (unsigned short)(u >> 16);
}

static __device__ __forceinline__ float sigm(float x) {
  return 1.0f / (1.0f + __expf(-x));
}
// NaN-safe fast tanh: uses |x| so exp never produces inf-inf.
static __device__ __forceinline__ float tanh_fast(float x) {
  float e = __expf(2.0f * fabsf(x));
  float t = 1.0f - 2.0f / (e + 1.0f);
  return copysignf(t, x);
}

// ---------------- fp32 -> bf16 conversion (vectorized x4, grid-stride) ------
__global__ void conv_f2b(const float* __restrict__ in,
                         unsigned short* __restrict__ out, int n4) {
  int idx = blockIdx.x * blockDim.x + threadIdx.x;
  int stride = gridDim.x * blockDim.x;
  for (int i = idx; i < n4; i += stride) {
    float4 v = reinterpret_cast<const float4*>(in)[i];
    ushort4 o;
    o.x = f2b_rne(v.x); o.y = f2b_rne(v.y);
    o.z = f2b_rne(v.z); o.w = f2b_rne(v.w);
    reinterpret_cast<ushort4*>(out)[i] = o;
  }
}

// ---------------- hhb[l][b][g] = b_ih[g] + b_hh[g] + h0[l,b,:] . w_hh[g,:] ---
// One WAVE per gate-row g: lanes split K (coalesced float4 reads of w_hh[g],
// held in registers across the b-loop); butterfly-reduce per b.
// grid (512, 2), block 256 (4 waves = 4 g per block).
__global__ void hh_bias(const float* __restrict__ h0,
                        const float* __restrict__ whh0, const float* __restrict__ whh1,
                        const float* __restrict__ bih0, const float* __restrict__ bhh0,
                        const float* __restrict__ bih1, const float* __restrict__ bhh1,
                        float* __restrict__ hhb) {
  const int l = blockIdx.y;
  const int wid = threadIdx.x >> 6;
  const int lane = threadIdx.x & 63;
  const int g = blockIdx.x * 4 + wid;  // 0..2047
  const float* wh = l ? whh1 : whh0;
  const float* bi = l ? bih1 : bih0;
  const float* bh = l ? bhh1 : bhh0;
  const float4* wr = reinterpret_cast<const float4*>(wh + (size_t)g * H_DIM);
  float4 w0 = wr[lane * 2];
  float4 w1 = wr[lane * 2 + 1];
  float bias = bi[g] + bh[g];
  const float* h0l = h0 + (size_t)l * B_DIM * H_DIM;
  for (int b = 0; b < B_DIM; ++b) {
    const float4* hr = reinterpret_cast<const float4*>(h0l + (size_t)b * H_DIM);
    float4 a0 = hr[lane * 2];
    float4 a1 = hr[lane * 2 + 1];
    float acc = a0.x * w0.x + a0.y * w0.y + a0.z * w0.z + a0.w * w0.w +
                a1.x * w1.x + a1.y * w1.y + a1.z * w1.z + a1.w * w1.w;
#pragma unroll
    for (int off = 32; off; off >>= 1) acc += __shfl_xor(acc, off);
    if (lane == 0) hhb[((size_t)l * B_DIM + b) * 2048 + g] = acc + bias;
  }
}

// ---------------- fused LSTM-layer GEMM -------------------------------------
// gates[m, gate*512+h] = sum_k A[m,k] * W[gate*512+h, k]   (B^T layout)
// Block tile: 128 rows x 32 h x 4 gates (128x128 eff).  4 waves in 2x2:
//   wave (wr,wc): rows wr*64..+64, h-sub wc*16..+16, all 4 gates.
//   acc[4][4]: [row-frag][gate] -> all 4 gates of one (m,h) in ONE lane.
// LDS: XOR-swizzled k-chunks (chunk ^= row&7) applied on the global SOURCE
// address during global_load_lds (linear dest) and on the ds_read address.
// Grid: 8192 blocks 1D, XCD-chunked swizzle (each XCD gets 1024 consecutive
// wg = 64 m-panels x all 16 h-tiles -> A-panel sharers co-resident per L2).
template <int LAYER>
__global__ __launch_bounds__(256, 2) void lstm_gemm(
    const unsigned short* __restrict__ Abf,   // [65536, 512] bf16
    const unsigned short* __restrict__ Wbf,   // [2048, 512]  bf16
    const float* __restrict__ hhb,            // [64, 2048] this layer
    const float* __restrict__ c0l,            // [64, 512]  this layer
    unsigned short* __restrict__ hy_bf,       // layer0: bf16 out (ws)
    float* __restrict__ out_hy,               // layer1: fp32 out (d_out)
    float* __restrict__ out_lasth,            // [64,512] this layer
    float* __restrict__ out_lastc) {          // [64,512] this layer
  __shared__ __attribute__((aligned(16))) unsigned short Alds[128 * 64];
  __shared__ __attribute__((aligned(16))) unsigned short Blds[128 * 64];

  const int tid = threadIdx.x;
  const int lane = tid & 63;
  const int wid = tid >> 6;
  const int wr = wid >> 1, wc = wid & 1;

  // XCD chunked swizzle (bijective: 8192 % 8 == 0)
  const int lin = blockIdx.x;
  const int wg = (lin & 7) * 1024 + (lin >> 3);
  const int bh = wg & 15;    // h-tile (sharers of one A-panel are consecutive)
  const int bm = wg >> 4;    // m-tile
  const int m0 = bm * 128;
  const int h0v = bh * 32;
  const int lane_lo = lane & 15, lane_hi = lane >> 4;
  const int srow = tid >> 3;   // 0..31
  const int slot = tid & 7;

  f32x4 acc[4][4] = {};

  for (int ks = 0; ks < 8; ++ks) {
    const int k0 = ks * 64;
    // stage A tile [128][64] (linear LDS dest, inverse-swizzled source chunk)
#pragma unroll
    for (int i = 0; i < 4; ++i) {
      int row = i * 32 + srow;
      int sch = slot ^ (row & 7);
      const unsigned short* src = Abf + (size_t)(m0 + row) * 512 + k0 + sch * 8;
      char* dst = (char*)Alds + i * 4096 + wid * 1024;  // wave-uniform base
      __builtin_amdgcn_global_load_lds((const glob_void_t*)src, (lds_void_t*)dst, 16, 0, 0);
    }
    // stage B tile: eff-row n -> W row (n>>5)*512 + h0 + (n&31)
#pragma unroll
    for (int i = 0; i < 4; ++i) {
      int n = i * 32 + srow;
      int sch = slot ^ (n & 7);
      int wrow = (n >> 5) * H_DIM + h0v + (n & 31);
      const unsigned short* src = Wbf + (size_t)wrow * 512 + k0 + sch * 8;
      char* dst = (char*)Blds + i * 4096 + wid * 1024;
      __builtin_amdgcn_global_load_lds((const glob_void_t*)src, (lds_void_t*)dst, 16, 0, 0);
    }
    __syncthreads();

#pragma unroll
    for (int kk = 0; kk < 2; ++kk) {
      const int cbase = kk * 4 + lane_hi;  // k-chunk index (8 bf16 per chunk)
      short8 aF[4];
#pragma unroll
      for (int r = 0; r < 4; ++r) {
        int row = wr * 64 + r * 16 + lane_lo;
        aF[r] = *reinterpret_cast<const short8*>(
            (const char*)Alds + row * 128 + ((cbase ^ (row & 7)) << 4));
      }
      short8 bF[4];
#pragma unroll
      for (int g = 0; g < 4; ++g) {
        int n = g * 32 + wc * 16 + lane_lo;
        bF[g] = *reinterpret_cast<const short8*>(
            (const char*)Blds + n * 128 + ((cbase ^ (n & 7)) << 4));
      }
#pragma unroll
      for (int r = 0; r < 4; ++r)
#pragma unroll
        for (int g = 0; g < 4; ++g)
          acc[r][g] = __builtin_amdgcn_mfma_f32_16x16x32_bf16(aF[r], bF[g], acc[r][g], 0, 0, 0);
    }
    __syncthreads();
  }

  // fused gate epilogue: fragment index IS the gate
  const int h = h0v + wc * 16 + lane_lo;
#pragma unroll
  for (int r = 0; r < 4; ++r) {
#pragma unroll
    for (int j = 0; j < 4; ++j) {
      int m = m0 + wr * 64 + r * 16 + lane_hi * 4 + j;
      int b = m & (B_DIM - 1);
      bool isLast = (m >> 6) == (T_DIM - 1);
      const float* hb = hhb + (size_t)b * 2048;
      float gi = acc[r][0][j] + hb[h];
      float gf = acc[r][1][j] + hb[512 + h];
      float gg = acc[r][2][j] + hb[1024 + h];
      float go = acc[r][3][j] + hb[1536 + h];
      float iv = sigm(gi), fv = sigm(gf), gv = tanh_fast(gg), ov = sigm(go);
      float cv = fv * c0l[b * H_DIM + h] + iv * gv;
      float hv = ov * tanh_fast(cv);
      if (LAYER == 0) {
        hy_bf[(size_t)m * H_DIM + h] = f2b_rne(hv);
      } else {
        out_hy[(size_t)m * H_DIM + h] = hv;
      }
      if (isLast) {
        out_lasth[b * H_DIM + h] = hv;
        out_lastc[b * H_DIM + h] = cv;
      }
    }
  }
}

extern "C" void kernel_launch(void* const* d_in, const int* in_sizes, int n_in,
                              void* d_out, int out_size, void* d_ws, size_t ws_size,
                              hipStream_t stream) {
  const float* x    = (const float*)d_in[0];
  const float* h0   = (const float*)d_in[1];
  const float* c0   = (const float*)d_in[2];
  const float* wih0 = (const float*)d_in[3];
  const float* whh0 = (const float*)d_in[4];
  const float* bih0 = (const float*)d_in[5];
  const float* bhh0 = (const float*)d_in[6];
  const float* wih1 = (const float*)d_in[7];
  const float* whh1 = (const float*)d_in[8];
  const float* bih1 = (const float*)d_in[9];
  const float* bhh1 = (const float*)d_in[10];
  float* out = (float*)d_out;

  // workspace layout (bytes)
  char* ws = (char*)d_ws;
  unsigned short* x_bf   = (unsigned short*)(ws);              // 67108864 B
  unsigned short* hy0_bf = (unsigned short*)(ws + 67108864);   // 67108864 B
  unsigned short* w0_bf  = (unsigned short*)(ws + 134217728);  // 2097152 B
  unsigned short* w1_bf  = (unsigned short*)(ws + 136314880);  // 2097152 B
  float*          hhb    = (float*)(ws + 138412032);           // 1048576 B

  conv_f2b<<<2048, 256, 0, stream>>>(x, x_bf, 33554432 / 4);
  conv_f2b<<<512, 256, 0, stream>>>(wih0, w0_bf, 1048576 / 4);
  conv_f2b<<<512, 256, 0, stream>>>(wih1, w1_bf, 1048576 / 4);
  hh_bias<<<dim3(512, 2), 256, 0, stream>>>(h0, whh0, whh1, bih0, bhh0, bih1, bhh1, hhb);

  float* res   = out;                         // [65536, 512]
  float* lasth = out + 33554432;              // [2, 64, 512]
  float* lastc = out + 33554432 + 65536;      // [2, 64, 512]

  lstm_gemm<0><<<8192, 256, 0, stream>>>(
      x_bf, w0_bf, hhb, c0, hy0_bf, nullptr, lasth, lastc);
  lstm_gemm<1><<<8192, 256, 0, stream>>>(
      hy0_bf, w1_bf, hhb + 64 * 2048, c0 + 64 * 512, nullptr, res,
      lasth + 64 * 512, lastc + 64 * 512);
}